// Round 6
// baseline (225.643 us; speedup 1.0000x reference)
//
#include <hip/hip_runtime.h>
#include <hip/hip_bf16.h>

typedef float f32x4 __attribute__((ext_vector_type(4)));
typedef short s16x8 __attribute__((ext_vector_type(8)));
typedef unsigned int u32;
typedef u32 u32x4 __attribute__((ext_vector_type(4)));

#define BB 4096
#define FF 50
#define PP 1225
#define XS 68          // xs row stride (floats): 16B-aligned, spreads banks
#define NBLK 39        // ceil(1225/32) pair-blocks of 32
#define TPB 256

__global__ __launch_bounds__(TPB, 3)
void afm_mfma(const float* __restrict__ g_x, const float* __restrict__ g_W1,
              const float* __restrict__ g_b1, const float* __restrict__ g_w2,
              const float* __restrict__ g_p, float* __restrict__ g_out)
{
    __shared__ __align__(16) float xs[FF * XS];          // 13.6 KB
    __shared__ __align__(16) short wpkh[512 * 8];        // 8 KB  W1 hi frags
    __shared__ __align__(16) short wpkl[512 * 8];        // 8 KB  W1 lo frags
    __shared__ u32 ipk[1248];                            // 5 KB packed (i0 | i1<<16)
    __shared__ __align__(16) float b1s[64], w2s[64], ps[64];
    __shared__ float so_s[4], sw_s[4];

    const int tid = threadIdx.x;
    const int b = blockIdx.x;

    // ---- stage x[b] into LDS at stride XS ----
    {
        const float4* gx4 = (const float4*)(g_x + (size_t)b * FF * 64);
        for (int i = tid; i < FF * 16; i += TPB) {
            float4 v = gx4[i];
            int row = i >> 4, col = (i & 15) << 2;
            *(float4*)&xs[row * XS + col] = v;
        }
    }
    if (tid < 64) { b1s[tid] = g_b1[tid]; w2s[tid] = g_w2[tid]; ps[tid] = g_p[tid]; }

    // ---- pack W1 into MFMA A-fragment order, truncation-split hi/lo ----
    for (int e = tid; e < 512; e += TPB) {
        int t = e >> 8, rem = e & 255, ma = rem >> 6, ln = rem & 63;
        int gg = ln >> 4, col = ma * 16 + (ln & 15);
        s16x8 h, l;
        #pragma unroll
        for (int j = 0; j < 8; ++j) {
            float v = g_W1[(t * 32 + gg * 8 + j) * 64 + col];
            u32 vb = __float_as_uint(v);
            float lo = v - __uint_as_float(vb & 0xFFFF0000u);
            h[j] = (short)(vb >> 16);
            l[j] = (short)(__float_as_uint(lo) >> 16);
        }
        *(s16x8*)&wpkh[e * 8] = h;
        *(s16x8*)&wpkl[e * 8] = l;
    }

    // ---- pair index table (triu k=1), packed, padded to 1248 ----
    for (int p = tid; p < 1248; p += TPB) {
        u32 v = 0;
        if (p < PP) {
            int i = 0, base = 0;
            while (base + (FF - 1 - i) <= p) { base += FF - 1 - i; ++i; }
            v = (u32)i | ((u32)(p - base + i + 1) << 16);
        }
        ipk[p] = v;
    }
    __syncthreads();

    const int lane = tid & 63, wq = tid >> 6, g = lane >> 4, pl = lane & 15;

    // bias as MFMA C-init; w2 hoisted
    f32x4 bv[4], wv[4];
    #pragma unroll
    for (int ma = 0; ma < 4; ++ma) {
        bv[ma] = *(const f32x4*)&b1s[ma * 16 + g * 4];
        wv[ma] = *(const f32x4*)&w2s[ma * 16 + g * 4];
    }

    // row-broadcast p fragments (A[row][k] = p[k] for all rows), split hi/lo
    s16x8 pph[2], ppl[2];
    #pragma unroll
    for (int t = 0; t < 2; ++t)
        #pragma unroll
        for (int j = 0; j < 8; ++j) {
            float v = ps[t * 32 + g * 8 + j];
            u32 vb = __float_as_uint(v);
            float lo = v - __uint_as_float(vb & 0xFFFF0000u);
            pph[t][j] = (short)(vb >> 16);
            ppl[t][j] = (short)(__float_as_uint(lo) >> 16);
        }

    float s_w = 0.f, s_out = 0.f;

    // ---- main loop: per-wave independent 32-pair blocks, no barriers ----
    for (int blk = wq; blk < NBLK; blk += 4) {
        const int base = blk * 32;
        u32 q0 = ipk[base + pl], q1 = ipk[base + 16 + pl];
        int ia0 = q0 & 0xFFFFu, ib0 = q0 >> 16;
        int ia1 = q1 & 0xFFFFu, ib1 = q1 >> 16;

        f32x4 acc[2][4];
        #pragma unroll
        for (int nt = 0; nt < 2; ++nt)
            #pragma unroll
            for (int ma = 0; ma < 4; ++ma)
                acc[nt][ma] = bv[ma];
        f32x4 accg[2];
        {
            f32x4 z = {0.f, 0.f, 0.f, 0.f};
            accg[0] = z; accg[1] = z;
        }

        #pragma unroll
        for (int t = 0; t < 2; ++t) {
            #pragma unroll
            for (int nt = 0; nt < 2; ++nt) {
                int ra = nt ? ia1 : ia0, rb = nt ? ib1 : ib0;
                const float* x0 = &xs[ra * XS + t * 32 + g * 8];
                const float* x1 = &xs[rb * XS + t * 32 + g * 8];
                f32x4 a0 = *(const f32x4*)x0, a1 = *(const f32x4*)(x0 + 4);
                f32x4 c0 = *(const f32x4*)x1, c1 = *(const f32x4*)(x1 + 4);
                float pr[8];
                #pragma unroll
                for (int j = 0; j < 4; ++j) {
                    pr[j]     = a0[j] * c0[j];
                    pr[4 + j] = a1[j] * c1[j];
                }
                u32x4 hw, lw;
                #pragma unroll
                for (int w = 0; w < 4; ++w) {
                    u32 peb = __float_as_uint(pr[2 * w]);
                    u32 pob = __float_as_uint(pr[2 * w + 1]);
                    float loe = pr[2 * w]     - __uint_as_float(peb & 0xFFFF0000u);
                    float loo = pr[2 * w + 1] - __uint_as_float(pob & 0xFFFF0000u);
                    hw[w] = __builtin_amdgcn_perm(pob, peb, 0x07060302u);
                    lw[w] = __builtin_amdgcn_perm(__float_as_uint(loo),
                                                  __float_as_uint(loe), 0x07060302u);
                }
                s16x8 ph = __builtin_bit_cast(s16x8, hw);
                s16x8 pv = __builtin_bit_cast(s16x8, lw);
                #pragma unroll
                for (int ma = 0; ma < 4; ++ma) {
                    const s16x8 wh = *(const s16x8*)&wpkh[((t * 4 + ma) * 64 + lane) * 8];
                    const s16x8 wl = *(const s16x8*)&wpkl[((t * 4 + ma) * 64 + lane) * 8];
                    acc[nt][ma] = __builtin_amdgcn_mfma_f32_16x16x32_bf16(wh, ph, acc[nt][ma], 0, 0, 0);
                    acc[nt][ma] = __builtin_amdgcn_mfma_f32_16x16x32_bf16(wl, ph, acc[nt][ma], 0, 0, 0);
                    acc[nt][ma] = __builtin_amdgcn_mfma_f32_16x16x32_bf16(wh, pv, acc[nt][ma], 0, 0, 0);
                }
                // G_p = prod · p  on the matrix pipe (rows all broadcast to G)
                accg[nt] = __builtin_amdgcn_mfma_f32_16x16x32_bf16(pph[t], ph, accg[nt], 0, 0, 0);
                accg[nt] = __builtin_amdgcn_mfma_f32_16x16x32_bf16(ppl[t], ph, accg[nt], 0, 0, 0);
                accg[nt] = __builtin_amdgcn_mfma_f32_16x16x32_bf16(pph[t], pv, accg[nt], 0, 0, 0);
            }
        }

        // ---- logits: ReLU + w2 dot (bias already in acc), reduce over a ----
        float lg0 = 0.f, lg1 = 0.f;
        #pragma unroll
        for (int ma = 0; ma < 4; ++ma) {
            #pragma unroll
            for (int r = 0; r < 4; ++r) {
                lg0 = fmaf(fmaxf(acc[0][ma][r], 0.f), wv[ma][r], lg0);
                lg1 = fmaf(fmaxf(acc[1][ma][r], 0.f), wv[ma][r], lg1);
            }
        }
        lg0 += __shfl_xor(lg0, 16); lg0 += __shfl_xor(lg0, 32);
        lg1 += __shfl_xor(lg1, 16); lg1 += __shfl_xor(lg1, 32);
        if (base + pl >= PP)      lg0 = -1e30f;
        if (base + 16 + pl >= PP) lg1 = -1e30f;

        // ---- softmax without max subtraction (logits bounded ~|40| << 88) ----
        float e0 = __expf(lg0), e1 = __expf(lg1);
        s_w += e0 + e1;
        s_out = fmaf(e0, accg[0][0], fmaf(e1, accg[1][0], s_out));
    }

    // ---- wave finalize: reduce over the 16 pair-lanes (all g identical) ----
    s_w += __shfl_xor(s_w, 1); s_w += __shfl_xor(s_w, 2);
    s_w += __shfl_xor(s_w, 4); s_w += __shfl_xor(s_w, 8);
    s_out += __shfl_xor(s_out, 1); s_out += __shfl_xor(s_out, 2);
    s_out += __shfl_xor(s_out, 4); s_out += __shfl_xor(s_out, 8);
    if (lane == 0) { sw_s[wq] = s_w; so_s[wq] = s_out; }
    __syncthreads();

    if (tid == 0) {
        float sg = sw_s[0] + sw_s[1] + sw_s[2] + sw_s[3];
        float so = so_s[0] + so_s[1] + so_s[2] + so_s[3];
        g_out[b] = so / sg;
    }
}

extern "C" void kernel_launch(void* const* d_in, const int* in_sizes, int n_in,
                              void* d_out, int out_size, void* d_ws, size_t ws_size,
                              hipStream_t stream) {
    const float* g_x  = (const float*)d_in[0];
    const float* g_W1 = (const float*)d_in[1];
    const float* g_b1 = (const float*)d_in[2];
    const float* g_w2 = (const float*)d_in[3];
    const float* g_p  = (const float*)d_in[4];
    float* g_out = (float*)d_out;
    afm_mfma<<<BB, TPB, 0, stream>>>(g_x, g_W1, g_b1, g_w2, g_p, g_out);
}

// Round 7
// 155.451 us; speedup vs baseline: 1.4515x; 1.4515x over previous
//
#include <hip/hip_runtime.h>
#include <hip/hip_bf16.h>

typedef float f32x4 __attribute__((ext_vector_type(4)));
typedef short s16x8 __attribute__((ext_vector_type(8)));
typedef unsigned int u32;
typedef u32 u32x4 __attribute__((ext_vector_type(4)));

#define BB 4096
#define FF 50
#define PP 1225
#define XS 68          // xs row stride (floats): 16B-aligned, spreads banks
#define NBLK 39        // ceil(1225/32) pair-blocks of 32
#define TPB 256

__global__ __launch_bounds__(TPB, 2)
void afm_mfma(const float* __restrict__ g_x, const float* __restrict__ g_W1,
              const float* __restrict__ g_b1, const float* __restrict__ g_w2,
              const float* __restrict__ g_p, float* __restrict__ g_out)
{
    __shared__ __align__(16) float xs[FF * XS];          // 13.6 KB
    __shared__ __align__(16) short wpkh[512 * 8];        // 8 KB  W1 hi frags
    __shared__ __align__(16) short wpkl[512 * 8];        // 8 KB  W1 lo frags
    __shared__ u32 ipk[1248];                            // 5 KB packed (i0 | i1<<16)
    __shared__ __align__(16) float b1s[64], w2s[64], ps[64];
    __shared__ float so_s[4], sw_s[4];

    const int tid = threadIdx.x;
    const int b = blockIdx.x;

    // ---- stage x[b] into LDS at stride XS ----
    {
        const float4* gx4 = (const float4*)(g_x + (size_t)b * FF * 64);
        for (int i = tid; i < FF * 16; i += TPB) {
            float4 v = gx4[i];
            int row = i >> 4, col = (i & 15) << 2;
            *(float4*)&xs[row * XS + col] = v;
        }
    }
    if (tid < 64) { b1s[tid] = g_b1[tid]; w2s[tid] = g_w2[tid]; ps[tid] = g_p[tid]; }

    // ---- pack W1 into MFMA A-fragment order, truncation-split hi/lo ----
    for (int e = tid; e < 512; e += TPB) {
        int t = e >> 8, rem = e & 255, ma = rem >> 6, ln = rem & 63;
        int gg = ln >> 4, col = ma * 16 + (ln & 15);
        s16x8 h, l;
        #pragma unroll
        for (int j = 0; j < 8; ++j) {
            float v = g_W1[(t * 32 + gg * 8 + j) * 64 + col];
            u32 vb = __float_as_uint(v);
            float lo = v - __uint_as_float(vb & 0xFFFF0000u);
            h[j] = (short)(vb >> 16);
            l[j] = (short)(__float_as_uint(lo) >> 16);
        }
        *(s16x8*)&wpkh[e * 8] = h;
        *(s16x8*)&wpkl[e * 8] = l;
    }

    // ---- pair index table (triu k=1), packed, padded to 1248 ----
    for (int p = tid; p < 1248; p += TPB) {
        u32 v = 0;
        if (p < PP) {
            int i = 0, base = 0;
            while (base + (FF - 1 - i) <= p) { base += FF - 1 - i; ++i; }
            v = (u32)i | ((u32)(p - base + i + 1) << 16);
        }
        ipk[p] = v;
    }
    __syncthreads();

    const int lane = tid & 63, wq = tid >> 6, g = lane >> 4, pl = lane & 15;

    // bias as MFMA C-init; w2 hoisted
    f32x4 bv[4], wv[4];
    #pragma unroll
    for (int ma = 0; ma < 4; ++ma) {
        bv[ma] = *(const f32x4*)&b1s[ma * 16 + g * 4];
        wv[ma] = *(const f32x4*)&w2s[ma * 16 + g * 4];
    }

    // row-broadcast p fragments (A[row][k] = p[k] for all rows), split hi/lo
    s16x8 pph[2], ppl[2];
    #pragma unroll
    for (int t = 0; t < 2; ++t)
        #pragma unroll
        for (int j = 0; j < 8; ++j) {
            float v = ps[t * 32 + g * 8 + j];
            u32 vb = __float_as_uint(v);
            float lo = v - __uint_as_float(vb & 0xFFFF0000u);
            pph[t][j] = (short)(vb >> 16);
            ppl[t][j] = (short)(__float_as_uint(lo) >> 16);
        }

    float s_w = 0.f, s_out = 0.f;

    // ---- main loop: per-wave independent 32-pair blocks, no barriers ----
    for (int blk = wq; blk < NBLK; blk += 4) {
        const int base = blk * 32;
        u32 q0 = ipk[base + pl], q1 = ipk[base + 16 + pl];
        int ia0 = q0 & 0xFFFFu, ib0 = q0 >> 16;
        int ia1 = q1 & 0xFFFFu, ib1 = q1 >> 16;

        f32x4 acc[2][4];
        #pragma unroll
        for (int nt = 0; nt < 2; ++nt)
            #pragma unroll
            for (int ma = 0; ma < 4; ++ma)
                acc[nt][ma] = bv[ma];
        f32x4 accg[2];
        {
            f32x4 z = {0.f, 0.f, 0.f, 0.f};
            accg[0] = z; accg[1] = z;
        }

        #pragma unroll
        for (int t = 0; t < 2; ++t) {
            #pragma unroll
            for (int nt = 0; nt < 2; ++nt) {
                int ra = nt ? ia1 : ia0, rb = nt ? ib1 : ib0;
                const float* x0 = &xs[ra * XS + t * 32 + g * 8];
                const float* x1 = &xs[rb * XS + t * 32 + g * 8];
                f32x4 a0 = *(const f32x4*)x0, a1 = *(const f32x4*)(x0 + 4);
                f32x4 c0 = *(const f32x4*)x1, c1 = *(const f32x4*)(x1 + 4);
                float pr[8];
                #pragma unroll
                for (int j = 0; j < 4; ++j) {
                    pr[j]     = a0[j] * c0[j];
                    pr[4 + j] = a1[j] * c1[j];
                }
                u32x4 hw, lw;
                #pragma unroll
                for (int w = 0; w < 4; ++w) {
                    u32 peb = __float_as_uint(pr[2 * w]);
                    u32 pob = __float_as_uint(pr[2 * w + 1]);
                    float loe = pr[2 * w]     - __uint_as_float(peb & 0xFFFF0000u);
                    float loo = pr[2 * w + 1] - __uint_as_float(pob & 0xFFFF0000u);
                    hw[w] = __builtin_amdgcn_perm(pob, peb, 0x07060302u);
                    lw[w] = __builtin_amdgcn_perm(__float_as_uint(loo),
                                                  __float_as_uint(loe), 0x07060302u);
                }
                s16x8 ph = __builtin_bit_cast(s16x8, hw);
                s16x8 pv = __builtin_bit_cast(s16x8, lw);
                #pragma unroll
                for (int ma = 0; ma < 4; ++ma) {
                    const s16x8 wh = *(const s16x8*)&wpkh[((t * 4 + ma) * 64 + lane) * 8];
                    const s16x8 wl = *(const s16x8*)&wpkl[((t * 4 + ma) * 64 + lane) * 8];
                    acc[nt][ma] = __builtin_amdgcn_mfma_f32_16x16x32_bf16(wh, ph, acc[nt][ma], 0, 0, 0);
                    acc[nt][ma] = __builtin_amdgcn_mfma_f32_16x16x32_bf16(wl, ph, acc[nt][ma], 0, 0, 0);
                    acc[nt][ma] = __builtin_amdgcn_mfma_f32_16x16x32_bf16(wh, pv, acc[nt][ma], 0, 0, 0);
                }
                // G_p = prod · p  on the matrix pipe (rows all broadcast to G)
                accg[nt] = __builtin_amdgcn_mfma_f32_16x16x32_bf16(pph[t], ph, accg[nt], 0, 0, 0);
                accg[nt] = __builtin_amdgcn_mfma_f32_16x16x32_bf16(ppl[t], ph, accg[nt], 0, 0, 0);
                accg[nt] = __builtin_amdgcn_mfma_f32_16x16x32_bf16(pph[t], pv, accg[nt], 0, 0, 0);
            }
        }

        // ---- logits: ReLU + w2 dot (bias already in acc), reduce over a ----
        float lg0 = 0.f, lg1 = 0.f;
        #pragma unroll
        for (int ma = 0; ma < 4; ++ma) {
            #pragma unroll
            for (int r = 0; r < 4; ++r) {
                lg0 = fmaf(fmaxf(acc[0][ma][r], 0.f), wv[ma][r], lg0);
                lg1 = fmaf(fmaxf(acc[1][ma][r], 0.f), wv[ma][r], lg1);
            }
        }
        lg0 += __shfl_xor(lg0, 16); lg0 += __shfl_xor(lg0, 32);
        lg1 += __shfl_xor(lg1, 16); lg1 += __shfl_xor(lg1, 32);
        if (base + pl >= PP)      lg0 = -1e30f;
        if (base + 16 + pl >= PP) lg1 = -1e30f;

        // ---- softmax without max subtraction (logits bounded ~|40| << 88) ----
        float e0 = __expf(lg0), e1 = __expf(lg1);
        s_w += e0 + e1;
        s_out = fmaf(e0, accg[0][0], fmaf(e1, accg[1][0], s_out));
    }

    // ---- wave finalize: reduce over the 16 pair-lanes (all g identical) ----
    s_w += __shfl_xor(s_w, 1); s_w += __shfl_xor(s_w, 2);
    s_w += __shfl_xor(s_w, 4); s_w += __shfl_xor(s_w, 8);
    s_out += __shfl_xor(s_out, 1); s_out += __shfl_xor(s_out, 2);
    s_out += __shfl_xor(s_out, 4); s_out += __shfl_xor(s_out, 8);
    if (lane == 0) { sw_s[wq] = s_w; so_s[wq] = s_out; }
    __syncthreads();

    if (tid == 0) {
        float sg = sw_s[0] + sw_s[1] + sw_s[2] + sw_s[3];
        float so = so_s[0] + so_s[1] + so_s[2] + so_s[3];
        g_out[b] = so / sg;
    }
}

extern "C" void kernel_launch(void* const* d_in, const int* in_sizes, int n_in,
                              void* d_out, int out_size, void* d_ws, size_t ws_size,
                              hipStream_t stream) {
    const float* g_x  = (const float*)d_in[0];
    const float* g_W1 = (const float*)d_in[1];
    const float* g_b1 = (const float*)d_in[2];
    const float* g_w2 = (const float*)d_in[3];
    const float* g_p  = (const float*)d_in[4];
    float* g_out = (float*)d_out;
    afm_mfma<<<BB, TPB, 0, stream>>>(g_x, g_W1, g_b1, g_w2, g_p, g_out);
}